// Round 11
// baseline (170.036 us; speedup 1.0000x reference)
//
#include <hip/hip_runtime.h>

#define DD 64
#define HH 256
#define WW 256
#define NN (DD*HH*WW)   // 4194304
#define GHS 4096        // stats-hash slots per copy (power of 2)
#define NCOPY 16        // replicated stats hashes (contention spread)
#define PHS 131072      // global pair-hash slots (power of 2, 64-bit keys)
#define NSEG (NN/32)    // 131072 bitmask words
#define NRUN (NSEG*16)  // 2097152 run slots (max 16 runs per 32-bit word)

// tile for local CCL phase
#define TZ 8
#define TY 32
#define TX 32

// face-voxel enumeration for cross-tile pass
#define CA 458752            // 7 * 65536   (z-faces)
#define CB 114688            // 7 * 16384   (each of y0/y31/x0/x31 faces)
#define CFACE (CA + 4*CB)    // 917504 = 3584 * 256

// per-face backward offset subsets:
// T0 rows 0-8: all dz=-1 ; T1 rows 9-14: dy=-1 ; T2 rows 15-17: dy=+1(dz=-1)
// T3 rows 18-22: dx=-1   ; T4 rows 23-26: dx=+1
__device__ const signed char Foff[27][3] = {
  {-1,-1,-1},{-1,-1,0},{-1,-1,1},{-1,0,-1},{-1,0,0},{-1,0,1},{-1,1,-1},{-1,1,0},{-1,1,1},
  {-1,-1,-1},{-1,-1,0},{-1,-1,1},{0,-1,-1},{0,-1,0},{0,-1,1},
  {-1,1,-1},{-1,1,0},{-1,1,1},
  {-1,-1,-1},{-1,0,-1},{-1,1,-1},{0,-1,-1},{0,0,-1},
  {-1,-1,1},{-1,0,1},{-1,1,1},{0,-1,1}};
__device__ const int Fst[5] = {0, 9, 15, 18, 23};
__device__ const int Fct[5] = {9, 6, 3, 5, 4};

// ---------------- global union-find (run space) ----------------
// Safety: every write stores an ancestor and preserves P[x] <= x; 4B accesses
// are HW-atomic, so concurrent halving stores cannot lose connectivity.
__device__ __forceinline__ int ufind(int* P, int x){
  int p = P[x];
  while (p != x){
    int gp = P[p];
    if (gp != p) P[x] = gp;   // path halving
    x = gp;
    p = P[x];
  }
  return x;
}

__device__ __forceinline__ void uunion(int* P, int a, int b){
  while (true){
    a = ufind(P, a);
    b = ufind(P, b);
    if (a == b) return;
    if (a < b){ int t = a; a = b; b = t; }   // link big -> small
    int old = atomicMin(&P[a], b);
    if (old == a) return;
    a = old;
  }
}

// ---------------- LDS union-find with +1-padded addressing ----------------
// values are node ids (row<<5|x); addresses are padded to 33 ints/row
__device__ __forceinline__ int slp(int v){ return ((v >> 5) * 33) + (v & 31); }

__device__ __forceinline__ int lfind_ro(const int* P, int x){
  int p = P[slp(x)];
  while (p != x){ x = p; p = P[slp(x)]; }
  return x;
}

__device__ __forceinline__ int lfind(int* P, int x){
  int p = P[slp(x)];
  while (p != x){
    int gp = P[slp(p)];
    if (gp != p) P[slp(x)] = gp;
    x = gp;
    p = P[slp(x)];
  }
  return x;
}

__device__ __forceinline__ void lunion(int* P, int a, int b){
  while (true){
    a = lfind(P, a);
    b = lfind(P, b);
    if (a == b) return;
    if (a < b){ int t = a; a = b; b = t; }
    int old = atomicMin(&P[slp(a)], b);
    if (old == a) return;
    a = old;
  }
}

// run start of bit x in mask m (bit x must be set)
__device__ __forceinline__ int run_start(unsigned m, int x){
  unsigned zb = (~m) & ((x == 0) ? 0u : ((1u << x) - 1u));
  return (zb == 0) ? 0 : (32 - __builtin_clz(zb));
}

// run index of bit x in mask m (bit x must be set); starts = m & ~(m<<1)
__device__ __forceinline__ int run_idx(unsigned starts, int x){
  return __popc(starts & ((2u << x) - 1u)) - 1;
}

__device__ __forceinline__ int refl(int v, int L){ return v < 0 ? 1 : (v >= L ? L - 2 : v); }

// ---------------- phase A: run-granular tile-local CCL in LDS ----------------
__global__ __launch_bounds__(1024) void k_local(const float* __restrict__ in,
                                                int* __restrict__ runp,
                                                unsigned* __restrict__ fgbits,
                                                int* __restrict__ hkey,
                                                int* __restrict__ harea,
                                                int* __restrict__ hper,
                                                unsigned long long* __restrict__ ph){
  __shared__ int sl[33 * 256];            // padded union-find (run-start entries only)
  __shared__ unsigned srow[256];          // fg mask per (lz,ly) row
  const int t = threadIdx.x;
  const int b = blockIdx.x;               // 512 tiles: 8 x 8 x 8
  const int z0 = (b >> 6) * TZ;
  const int y0 = ((b >> 3) & 7) * TY;
  const int x0 = (b & 7) * TX;

  // init 16 stats-hash copies (16*4096 = 65536 = 64 blocks x 1024)
  if (b < (NCOPY * GHS) / 1024){ int j = b * 1024 + t; hkey[j] = -1; harea[j] = 0; hper[j] = 0; }
  { int j = b * 1024 + t; if (j < PHS) ph[j] = ~0ULL; }   // pair hash sentinel

  // blocked mapping: thread t owns one byte (8 voxels) of row (t>>2)
  const int row = t >> 2;                 // (lz<<5)|ly
  const int xb  = (t & 3) * 8;
  const int lz  = row >> 5, ly = row & 31;
  const int gi0 = ((z0 + lz) << 16) | ((y0 + ly) << 8) | (x0 + xb);

  // A1: vectorized load -> fg byte -> row mask via 2 shuffle rounds
  float4 f0 = *(const float4*)(in + gi0);
  float4 f1 = *(const float4*)(in + gi0 + 4);
  int by = (f0.x > 0.5f)        | ((f0.y > 0.5f) << 1) |
           ((f0.z > 0.5f) << 2) | ((f0.w > 0.5f) << 3) |
           ((f1.x > 0.5f) << 4) | ((f1.y > 0.5f) << 5) |
           ((f1.z > 0.5f) << 6) | ((f1.w > 0.5f) << 7);
  int v1 = by | (__shfl_xor(by, 1) << 8);
  int v2 = v1 | (__shfl_xor(v1, 2) << 16);
  if ((t & 3) == 0){
    srow[row] = (unsigned)v2;
    fgbits[((z0 + lz) << 11) | ((y0 + ly) << 3) | (x0 >> 5)] = (unsigned)v2;
  }
  __syncthreads();

  const unsigned m = srow[row];
  const unsigned starts = m & ~(m << 1);           // all run starts of this row
  const unsigned sm = starts & (0xFFu << xb);      // starts within this thread's byte

  // A2: init ONLY run-start entries (the union-find never touches others)
  {
    unsigned w = sm;
    while (w){
      int s = __builtin_ctz(w); w &= w - 1;
      sl[slp((row << 5) | s)] = (row << 5) | s;
    }
  }
  __syncthreads();

  // A3: run-granular unions; thread owning the run START handles the whole run
  const int rel[4][2] = {{-1,-1},{-1,0},{-1,1},{0,-1}};   // (dz,dy)
  {
    unsigned w0 = sm;
    while (w0){
      int x = __builtin_ctz(w0); w0 &= w0 - 1;
      unsigned zs = (~m) >> x;
      int len = zs ? __builtin_ctz(zs) : (32 - x);
      int end = x + len - 1;
      unsigned long long wmask = ((1ull << (end + 2)) - 1) &
                                 ~((x == 0) ? 0ull : ((1ull << (x - 1)) - 1));
      int self = (row << 5) | x;
      #pragma unroll
      for (int r = 0; r < 4; r++){
        int zz = lz + rel[r][0], yy = ly + rel[r][1];
        if (zz < 0 || yy < 0 || yy >= TY) continue;
        int nrow = (zz << 5) | yy;
        unsigned mN = srow[nrow];
        unsigned wm = mN & (unsigned)wmask;
        while (wm){
          int bb = __builtin_ctz(wm);
          int ns = run_start(mN, bb);
          lunion(sl, self, (nrow << 5) | ns);
          unsigned t2 = (~mN) >> bb;
          int l2 = t2 ? __builtin_ctz(t2) : (32 - bb);
          unsigned long long clr = (bb + l2 >= 32) ? 0xffffffffull : ((1ull << (bb + l2)) - 1);
          wm &= ~(unsigned)clr;
        }
      }
    }
  }
  __syncthreads();

  // A4: per run start, resolve tile-local root and write ONE runp entry
  const int gseg = ((z0 + lz) << 11) | ((y0 + ly) << 3) | (x0 >> 5);
  {
    unsigned w = sm;
    while (w){
      int s = __builtin_ctz(w); w &= w - 1;
      int v = (row << 5) | s;
      int r = lfind_ro(sl, v);                 // read-only chase (sl stable after A3)
      int rrow = r >> 5, rx = r & 31;
      unsigned mr = srow[rrow];
      unsigned str = mr & ~(mr << 1);
      int rseg = ((z0 + (rrow >> 5)) << 11) | ((y0 + (rrow & 31)) << 3) | (x0 >> 5);
      runp[(gseg << 4) + run_idx(starts, s)] = (rseg << 4) + run_idx(str, rx);
    }
  }
}

// ---------------- phase B: face pass — dedup pairs + inline union ----------------
__device__ __forceinline__ void phash_union(unsigned long long* H, unsigned long long key,
                                            int* runp){
  unsigned h = (unsigned)((key * 0x9E3779B97F4A7C15ull) >> 47);   // [0, 2^17)
  while (true){
    unsigned long long old = atomicCAS(&H[h], ~0ULL, key);
    if (old == ~0ULL){ uunion(runp, (int)(key >> 32), (int)(key & 0xffffffffu)); return; }
    if (old == key) return;
    h = (h + 1) & (PHS - 1);
  }
}

__global__ __launch_bounds__(256) void k_pairs(int* __restrict__ runp,
                                               const unsigned* __restrict__ fgbits,
                                               unsigned long long* __restrict__ ph){
  __shared__ unsigned long long pk[256];    // per-block pair-dedup hash
  const int t = threadIdx.x;
  pk[t] = ~0ULL;
  __syncthreads();

  const int id = blockIdx.x * 256 + t;
  int z, y, x, ot;
  if (id < CA){ ot = 0; z = ((id >> 16) + 1) << 3; y = (id >> 8) & 255; x = id & 255; }
  else {
    int q = id - CA;
    int f = q >> 14;            // 0..27
    int r = q & 16383;
    int g = f / 7, mm = f % 7;
    if      (g == 0){ ot = 1; y = (mm + 1) << 5;  z = r >> 8; x = r & 255; }
    else if (g == 1){ ot = 2; y = (mm << 5) + 31; z = r >> 8; x = r & 255; }
    else if (g == 2){ ot = 3; x = (mm + 1) << 5;  z = r >> 8; y = r & 255; }
    else            { ot = 4; x = (mm << 5) + 31; z = r >> 8; y = r & 255; }
  }
  const int segS = (z << 11) | (y << 3) | (x >> 5);
  const unsigned mS = fgbits[segS];
  if ((mS >> (x & 31)) & 1){
    const unsigned stS = mS & ~(mS << 1);
    const int a = runp[(segS << 4) + run_idx(stS, x & 31)];   // tile-root runID
    unsigned long long lastkey = ~0ULL;                       // register dedup cache
    const int st = Fst[ot], en = st + Fct[ot];
    for (int k = st; k < en; k++){
      int zz = z + Foff[k][0], yy = y + Foff[k][1], xx = x + Foff[k][2];
      if (zz < 0 || yy < 0 || yy >= HH || xx < 0 || xx >= WW) continue;  // zz<DD: dz<=0
      int segN = (zz << 11) | (yy << 3) | (xx >> 5);
      unsigned mN = fgbits[segN];
      if (!((mN >> (xx & 31)) & 1)) continue;
      unsigned stN = mN & ~(mN << 1);
      int bl = runp[(segN << 4) + run_idx(stN, xx & 31)];
      int hi = a > bl ? a : bl, lo = a > bl ? bl : a;
      unsigned long long key = ((unsigned long long)(unsigned)hi << 32) | (unsigned)lo;
      if (key == lastkey) continue;
      lastkey = key;
      unsigned h = (unsigned)((key * 0x9E3779B97F4A7C15ull) >> 56);  // [0,256)
      bool done = false;
      for (int probe = 0; probe < 256; probe++){
        unsigned long long old = atomicCAS(&pk[h], ~0ULL, key);
        if (old == ~0ULL || old == key){ done = true; break; }
        h = (h + 1) & 255;
      }
      if (!done) phash_union(ph, key, runp);   // LDS hash full -> global
    }
  }
  __syncthreads();
  if (pk[t] != ~0ULL) phash_union(ph, pk[t], runp);
}

// ---------------- phase C: fused block-local boundary + stats ----------------
__device__ __forceinline__ void ghash_add(int* hkey, int* harea, int* hper,
                                          int key, int a, int p){
  unsigned h = ((unsigned)key * 2654435761u) >> 20;   // [0,4096)
  while (true){
    int old = atomicCAS(&hkey[h], -1, key);
    if (old == -1 || old == key){
      atomicAdd(&harea[h], a);
      if (p) atomicAdd(&hper[h], p);
      return;
    }
    h = (h + 1) & (GHS - 1);
  }
}

__global__ __launch_bounds__(1024) void k_stats(const int* __restrict__ runp,
                                                const unsigned* __restrict__ fgbits,
                                                int* __restrict__ hkey,
                                                int* __restrict__ harea,
                                                int* __restrict__ hper){
  __shared__ unsigned sfg[144];            // 3 z-planes x 6 y-rows x 8 s-words
  __shared__ unsigned sbnd[32];
  __shared__ int sk[256], sa[256], sp[256];
  const int t = threadIdx.x;
  const int b = blockIdx.x;                // 4096 blocks; block = 4 y-rows at one z
  const int z = b >> 6;
  const int y0 = (b & 63) * 4;

  if (t < 256){ sk[t] = -1; sa[t] = 0; sp[t] = 0; }
  if (t < 144){
    int p = t / 48, q = (t / 8) % 6, s = t & 7;
    int zz = refl(z + p - 1, DD), yy = refl(y0 + q - 1, HH);
    sfg[t] = fgbits[(zz << 11) | (yy << 3) | s];
  }
  __syncthreads();

  if (t < 32){
    int ry = t >> 3, s = t & 7;
    auto W  = [&](int p, int q){ return sfg[p * 48 + q * 8 + s]; };
    auto WL = [&](int p, int q){
      unsigned w = W(p, q);
      unsigned c = (s > 0) ? ((sfg[p * 48 + q * 8 + s - 1] >> 31) & 1u) : ((w >> 1) & 1u);
      return (w << 1) | c;
    };
    auto WR = [&](int p, int q){
      unsigned w = W(p, q);
      unsigned c = (s < 7) ? ((sfg[p * 48 + q * 8 + s + 1] & 1u) << 31) : ((w & 0x40000000u) << 1);
      return (w >> 1) | c;
    };
    int qm = ry, qc = ry + 1, qp = ry + 2;
    unsigned own = W(1, qc);
    unsigned e = W(0, qm) & W(0, qp) & W(2, qm) & W(2, qp);     // (±1,±1,0)
    e &= W(0, qc) & WL(0, qc) & WR(0, qc);                      // (-1,0,*)
    e &= W(2, qc) & WL(2, qc) & WR(2, qc);                      // (+1,0,*)
    e &= W(1, qm) & WL(1, qm) & WR(1, qm);                      // (0,-1,*)
    e &= W(1, qp) & WL(1, qp) & WR(1, qp);                      // (0,+1,*)
    e &= WL(1, qc) & WR(1, qc);                                 // (0,0,±1)
    sbnd[t] = own & ~e;
  }
  __syncthreads();

  const int x = t & 255, ry = t >> 8;
  const unsigned m = sfg[48 + (ry + 1) * 8 + (x >> 5)];   // own fg word (from LDS)
  int lab = -1, bnd = 0;
  if ((m >> (x & 31)) & 1){
    bnd = (sbnd[t >> 5] >> (t & 31)) & 1;
    unsigned st = m & ~(m << 1);
    int gseg = (z << 11) | ((y0 + ry) << 3) | (x >> 5);
    int idr = (gseg << 4) + run_idx(st, x & 31);
    // parallel READ-ONLY root resolution (chains short; latency hidden by TLP)
    lab = runp[idr];
    int p = runp[lab];
    while (p != lab){ lab = p; p = runp[lab]; }
  }

  // wave reduce-by-key over FINAL roots (typically 1-2 distinct per wave)
  const int lane = t & 63;
  unsigned long long fgm = __ballot(lab >= 0);
  unsigned long long bm  = __ballot(bnd != 0);
  unsigned long long act = fgm;
  while (act){
    int leader = (int)__ffsll(act) - 1;
    int llab = __shfl(lab, leader);
    unsigned long long match = __ballot(lab == llab) & fgm;
    if (lane == leader){
      int a = (int)__popcll(match);
      int p = (int)__popcll(match & bm);
      unsigned h = ((unsigned)llab * 2654435761u) >> 24;
      bool done = false;
      for (int probe = 0; probe < 256; probe++){
        int old = atomicCAS(&sk[h], -1, llab);
        if (old == -1 || old == llab){
          atomicAdd(&sa[h], a);
          if (p) atomicAdd(&sp[h], p);
          done = true; break;
        }
        h = (h + 1) & 255;
      }
      if (!done) ghash_add(hkey, harea, hper, llab, a, p);
    }
    act &= ~match;
  }
  __syncthreads();
  // flush to one of NCOPY replicated hashes (spread same-address atomics)
  const int c = (b & (NCOPY - 1)) * GHS;
  if (t < 256 && sk[t] >= 0) ghash_add(hkey + c, harea + c, hper + c, sk[t], sa[t], sp[t]);
}

// ---------------- phase D: parallel merge of copies 1..15 into copy 0 ----------------
__global__ __launch_bounds__(256) void k_merge(int* __restrict__ hkey,
                                               int* __restrict__ harea,
                                               int* __restrict__ hper){
  const int j = GHS + blockIdx.x * 256 + threadIdx.x;   // grid covers (NCOPY-1)*GHS
  int key = hkey[j];
  if (key >= 0) ghash_add(hkey, harea, hper, key, harea[j], hper[j]);
}

// ---------------- phase E: scan copy 0 + finalize ----------------
__global__ __launch_bounds__(256) void k_fin(const int* __restrict__ hkey,
                                             const int* __restrict__ harea,
                                             const int* __restrict__ hper,
                                             float* __restrict__ out){
  __shared__ float ssum[256];
  const int t = threadIdx.x;
  float s = 0.0f;
  for (int j = t; j < GHS; j += 256){
    if (hkey[j] >= 0){
      float a = (float)harea[j];
      float p = (float)hper[j];
      s += 12.566370614359172f * a / (p * p + 1e-5f);
    }
  }
  ssum[t] = s;
  __syncthreads();
  for (int w = 128; w > 0; w >>= 1){
    if (t < w) ssum[t] += ssum[t + w];
    __syncthreads();
  }
  if (t == 0){
    float comp = ssum[0] / 64.0f;
    out[0] = 1.0f / (comp + 1e-5f);
  }
}

// ---------------- launcher ----------------
extern "C" void kernel_launch(void* const* d_in, const int* in_sizes, int n_in,
                              void* d_out, int out_size, void* d_ws, size_t ws_size,
                              hipStream_t stream){
  const float* y = (const float*)d_in[0];
  char* w = (char*)d_ws;
  int* runp              = (int*)w;                    w += (size_t)NRUN * 4;        // 8 MiB
  unsigned long long* ph = (unsigned long long*)w;     w += (size_t)PHS * 8;         // 1 MiB
  int* hkey              = (int*)w;                    w += (size_t)NCOPY * GHS * 4; // 256 KiB
  int* harea             = (int*)w;                    w += (size_t)NCOPY * GHS * 4;
  int* hper              = (int*)w;                    w += (size_t)NCOPY * GHS * 4;
  unsigned* fgbits       = (unsigned*)w;               w += (size_t)NSEG * 4;        // 512 KiB
  float* out = (float*)d_out;

  hipLaunchKernelGGL(k_local, dim3(512),       dim3(1024), 0, stream, y, runp, fgbits, hkey, harea, hper, ph);
  hipLaunchKernelGGL(k_pairs, dim3(CFACE/256), dim3(256),  0, stream, runp, fgbits, ph);
  hipLaunchKernelGGL(k_stats, dim3(NN/1024),   dim3(1024), 0, stream, runp, fgbits, hkey, harea, hper);
  hipLaunchKernelGGL(k_merge, dim3((NCOPY-1)*GHS/256), dim3(256), 0, stream, hkey, harea, hper);
  hipLaunchKernelGGL(k_fin,   dim3(1),         dim3(256),  0, stream, hkey, harea, hper, out);
}

// Round 12
// 168.719 us; speedup vs baseline: 1.0078x; 1.0078x over previous
//
#include <hip/hip_runtime.h>

#define DD 64
#define HH 256
#define WW 256
#define NN (DD*HH*WW)   // 4194304
#define GHS 4096        // stats-hash slots per copy (power of 2)
#define NCOPY 16        // replicated stats hashes (contention spread)
#define PHS 131072      // global pair-hash slots (power of 2, 64-bit keys)
#define NSEG (NN/32)    // 131072 bitmask words

// tile for local CCL phase
#define TZ 8
#define TY 32
#define TX 32

// face-voxel enumeration for cross-tile pass
#define CA 458752            // 7 * 65536   (z-faces)
#define CB 114688            // 7 * 16384   (each of y0/y31/x0/x31 faces)
#define CFACE (CA + 4*CB)    // 917504 = 3584 * 256

// per-face backward offset subsets:
// T0 rows 0-8: all dz=-1 ; T1 rows 9-14: dy=-1 ; T2 rows 15-17: dy=+1(dz=-1)
// T3 rows 18-22: dx=-1   ; T4 rows 23-26: dx=+1
__device__ const signed char Foff[27][3] = {
  {-1,-1,-1},{-1,-1,0},{-1,-1,1},{-1,0,-1},{-1,0,0},{-1,0,1},{-1,1,-1},{-1,1,0},{-1,1,1},
  {-1,-1,-1},{-1,-1,0},{-1,-1,1},{0,-1,-1},{0,-1,0},{0,-1,1},
  {-1,1,-1},{-1,1,0},{-1,1,1},
  {-1,-1,-1},{-1,0,-1},{-1,1,-1},{0,-1,-1},{0,0,-1},
  {-1,-1,1},{-1,0,1},{-1,1,1},{0,-1,1}};
__device__ const int Fst[5] = {0, 9, 15, 18, 23};
__device__ const int Fct[5] = {9, 6, 3, 5, 4};

// ---------------- global union-find (voxel-label space) ----------------
// Safety: every write stores an ancestor and preserves P[x] <= x; 4B accesses
// are HW-atomic, so concurrent halving stores cannot lose connectivity.
__device__ __forceinline__ int ufind(int* P, int x){
  int p = P[x];
  while (p != x){
    int gp = P[p];
    if (gp != p) P[x] = gp;   // path halving
    x = gp;
    p = P[x];
  }
  return x;
}

__device__ __forceinline__ void uunion(int* P, int a, int b){
  while (true){
    a = ufind(P, a);
    b = ufind(P, b);
    if (a == b) return;
    if (a < b){ int t = a; a = b; b = t; }   // link big -> small
    int old = atomicMin(&P[a], b);
    if (old == a) return;
    a = old;
  }
}

// ---------------- LDS union-find, stride-33 padded addressing ----------------
// node id v = (row<<5)|x ; LDS slot = v + (v>>5) = row*33 + x  (bank-decorrelated)
__device__ __forceinline__ int pad(int v){ return v + (v >> 5); }

__device__ __forceinline__ int lfind_ro(const int* P, int x){
  int p = P[pad(x)];
  while (p != x){ x = p; p = P[pad(x)]; }
  return x;
}

__device__ __forceinline__ int lfind(int* P, int x){
  int p = P[pad(x)];
  while (p != x){
    int gp = P[pad(p)];
    if (gp != p) P[pad(x)] = gp;
    x = gp;
    p = P[pad(x)];
  }
  return x;
}

__device__ __forceinline__ void lunion(int* P, int a, int b){
  while (true){
    a = lfind(P, a);
    b = lfind(P, b);
    if (a == b) return;
    if (a < b){ int t = a; a = b; b = t; }
    int old = atomicMin(&P[pad(a)], b);
    if (old == a) return;
    a = old;
  }
}

// run start of bit x in mask m (bit x must be set)
__device__ __forceinline__ int run_start(unsigned m, int x){
  unsigned zb = (~m) & ((x == 0) ? 0u : ((1u << x) - 1u));
  return (zb == 0) ? 0 : (32 - __builtin_clz(zb));
}

__device__ __forceinline__ int refl(int v, int L){ return v < 0 ? 1 : (v >= L ? L - 2 : v); }

// ---------------- phase A: run-granular tile-local CCL in LDS ----------------
__global__ __launch_bounds__(1024) void k_local(const float* __restrict__ in,
                                                int* __restrict__ parent,
                                                unsigned* __restrict__ fgbits,
                                                int* __restrict__ hkey,
                                                int* __restrict__ harea,
                                                int* __restrict__ hper,
                                                unsigned long long* __restrict__ ph){
  __shared__ int sl[33 * 256];            // padded union-find (run-start entries only)
  __shared__ unsigned srow[256];          // fg mask per (lz,ly) row
  const int t = threadIdx.x;
  const int b = blockIdx.x;               // 512 tiles: 8 x 8 x 8
  const int z0 = (b >> 6) * TZ;
  const int y0 = ((b >> 3) & 7) * TY;
  const int x0 = (b & 7) * TX;

  // init 16 stats-hash copies (16*4096 = 65536 = 64 blocks x 1024)
  if (b < (NCOPY * GHS) / 1024){ int j = b * 1024 + t; hkey[j] = -1; harea[j] = 0; hper[j] = 0; }
  { int j = b * 1024 + t; if (j < PHS) ph[j] = ~0ULL; }   // pair hash sentinel

  // blocked mapping: thread t owns one byte (8 voxels) of row (t>>2)
  const int row = t >> 2;                 // (lz<<5)|ly
  const int xb  = (t & 3) * 8;
  const int lz  = row >> 5, ly = row & 31;
  const int gi0 = ((z0 + lz) << 16) | ((y0 + ly) << 8) | (x0 + xb);

  // A1: vectorized load -> fg byte -> row mask via 2 shuffle rounds
  float4 f0 = *(const float4*)(in + gi0);
  float4 f1 = *(const float4*)(in + gi0 + 4);
  int by = (f0.x > 0.5f)        | ((f0.y > 0.5f) << 1) |
           ((f0.z > 0.5f) << 2) | ((f0.w > 0.5f) << 3) |
           ((f1.x > 0.5f) << 4) | ((f1.y > 0.5f) << 5) |
           ((f1.z > 0.5f) << 6) | ((f1.w > 0.5f) << 7);
  int v1 = by | (__shfl_xor(by, 1) << 8);
  int v2 = v1 | (__shfl_xor(v1, 2) << 16);
  if ((t & 3) == 0){
    srow[row] = (unsigned)v2;
    fgbits[((z0 + lz) << 11) | ((y0 + ly) << 3) | (x0 >> 5)] = (unsigned)v2;
  }
  __syncthreads();

  const unsigned m = srow[row];
  const unsigned starts = m & ~(m << 1);           // all run starts of this row
  const unsigned sm = starts & (0xFFu << xb);      // starts within this thread's byte

  // A2: init ONLY run-start entries (the union-find never touches others)
  {
    unsigned w = sm;
    while (w){
      int s = __builtin_ctz(w); w &= w - 1;
      sl[pad((row << 5) | s)] = (row << 5) | s;
    }
  }
  __syncthreads();

  // A3: run-granular unions; thread owning the run START handles the whole run
  const int rel[4][2] = {{-1,-1},{-1,0},{-1,1},{0,-1}};   // (dz,dy)
  {
    unsigned w0 = sm;
    while (w0){
      int x = __builtin_ctz(w0); w0 &= w0 - 1;
      unsigned zs = (~m) >> x;
      int len = zs ? __builtin_ctz(zs) : (32 - x);
      int end = x + len - 1;
      unsigned long long wmask = ((1ull << (end + 2)) - 1) &
                                 ~((x == 0) ? 0ull : ((1ull << (x - 1)) - 1));
      int self = (row << 5) | x;
      #pragma unroll
      for (int r = 0; r < 4; r++){
        int zz = lz + rel[r][0], yy = ly + rel[r][1];
        if (zz < 0 || yy < 0 || yy >= TY) continue;
        int nrow = (zz << 5) | yy;
        unsigned mN = srow[nrow];
        unsigned wm = mN & (unsigned)wmask;
        while (wm){
          int bb = __builtin_ctz(wm);
          int ns = run_start(mN, bb);
          lunion(sl, self, (nrow << 5) | ns);
          unsigned t2 = (~mN) >> bb;
          int l2 = t2 ? __builtin_ctz(t2) : (32 - bb);
          unsigned long long clr = (bb + l2 >= 32) ? 0xffffffffull : ((1ull << (bb + l2)) - 1);
          wm &= ~(unsigned)clr;
        }
      }
    }
  }
  __syncthreads();

  // A3.5: flatten run starts (read-only find; one final write per run start)
  {
    unsigned w = sm;
    while (w){
      int s = __builtin_ctz(w); w &= w - 1;
      int v = (row << 5) | s;
      sl[pad(v)] = lfind_ro(sl, v);
    }
  }
  __syncthreads();

  // A4: per-run label read + translate (once per run), fill 8 voxels, int4 store
  int lab[8];
  int cur = -1;
  #pragma unroll
  for (int k = 0; k < 8; k++){
    int x = xb + k;
    if (!((m >> x) & 1)){ lab[k] = -1; cur = -1; continue; }
    if (cur < 0){
      int rs = (k == 0) ? run_start(m, x) : x;     // k>0 & prev clear -> x is a start
      int r = sl[pad((row << 5) | rs)];
      cur = ((z0 + (r >> 10)) << 16) | ((y0 + ((r >> 5) & 31)) << 8) | (x0 + (r & 31));
    }
    lab[k] = cur;
  }
  *(int4*)(parent + gi0)     = make_int4(lab[0], lab[1], lab[2], lab[3]);
  *(int4*)(parent + gi0 + 4) = make_int4(lab[4], lab[5], lab[6], lab[7]);
}

// ---------------- phase B: face pass — dedup pairs + inline union ----------------
__device__ __forceinline__ void phash_union(unsigned long long* H, unsigned long long key,
                                            int* parent){
  unsigned h = (unsigned)((key * 0x9E3779B97F4A7C15ull) >> 47);   // [0, 2^17)
  while (true){
    unsigned long long old = atomicCAS(&H[h], ~0ULL, key);
    if (old == ~0ULL){ uunion(parent, (int)(key >> 32), (int)(key & 0xffffffffu)); return; }
    if (old == key) return;
    h = (h + 1) & (PHS - 1);
  }
}

__global__ __launch_bounds__(256) void k_pairs(int* __restrict__ parent,
                                               const unsigned* __restrict__ fgbits,
                                               unsigned long long* __restrict__ ph){
  __shared__ unsigned long long pk[256];    // per-block pair-dedup hash
  const int t = threadIdx.x;
  pk[t] = ~0ULL;
  __syncthreads();

  const int id = blockIdx.x * 256 + t;
  int z, y, x, ot;
  if (id < CA){ ot = 0; z = ((id >> 16) + 1) << 3; y = (id >> 8) & 255; x = id & 255; }
  else {
    int q = id - CA;
    int f = q >> 14;            // 0..27
    int r = q & 16383;
    int g = f / 7, mm = f % 7;
    if      (g == 0){ ot = 1; y = (mm + 1) << 5;  z = r >> 8; x = r & 255; }
    else if (g == 1){ ot = 2; y = (mm << 5) + 31; z = r >> 8; x = r & 255; }
    else if (g == 2){ ot = 3; x = (mm + 1) << 5;  z = r >> 8; y = r & 255; }
    else            { ot = 4; x = (mm << 5) + 31; z = r >> 8; y = r & 255; }
  }
  const int i = (z << 16) | (y << 8) | x;
  if ((fgbits[(z << 11) | (y << 3) | (x >> 5)] >> (x & 31)) & 1){
    int a = parent[i];
    unsigned long long lastkey = ~0ULL;     // register dedup cache
    const int st = Fst[ot], en = st + Fct[ot];
    for (int k = st; k < en; k++){
      int zz = z + Foff[k][0], yy = y + Foff[k][1], xx = x + Foff[k][2];
      if (zz < 0 || yy < 0 || yy >= HH || xx < 0 || xx >= WW) continue;  // zz<DD: dz<=0
      if (!((fgbits[(zz << 11) | (yy << 3) | (xx >> 5)] >> (xx & 31)) & 1)) continue;
      int bl = parent[(zz << 16) | (yy << 8) | xx];
      int hi = a > bl ? a : bl, lo = a > bl ? bl : a;
      unsigned long long key = ((unsigned long long)(unsigned)hi << 32) | (unsigned)lo;
      if (key == lastkey) continue;
      lastkey = key;
      unsigned h = (unsigned)((key * 0x9E3779B97F4A7C15ull) >> 56);  // [0,256)
      bool done = false;
      for (int probe = 0; probe < 256; probe++){
        unsigned long long old = atomicCAS(&pk[h], ~0ULL, key);
        if (old == ~0ULL || old == key){ done = true; break; }
        h = (h + 1) & 255;
      }
      if (!done) phash_union(ph, key, parent);   // LDS hash full -> global
    }
  }
  __syncthreads();
  if (pk[t] != ~0ULL) phash_union(ph, pk[t], parent);
}

// ---------------- phase C: fused block-local boundary + stats ----------------
__device__ __forceinline__ void ghash_add(int* hkey, int* harea, int* hper,
                                          int key, int a, int p){
  unsigned h = ((unsigned)key * 2654435761u) >> 20;   // [0,4096)
  while (true){
    int old = atomicCAS(&hkey[h], -1, key);
    if (old == -1 || old == key){
      atomicAdd(&harea[h], a);
      if (p) atomicAdd(&hper[h], p);
      return;
    }
    h = (h + 1) & (GHS - 1);
  }
}

__global__ __launch_bounds__(1024) void k_stats(const int* __restrict__ parent,
                                                const unsigned* __restrict__ fgbits,
                                                int* __restrict__ hkey,
                                                int* __restrict__ harea,
                                                int* __restrict__ hper){
  __shared__ unsigned sfg[144];            // 3 z-planes x 6 y-rows x 8 s-words
  __shared__ unsigned sbnd[32];
  __shared__ int sk[256], sa[256], sp[256];
  const int t = threadIdx.x;
  const int b = blockIdx.x;                // 4096 blocks; block = 4 y-rows at one z
  const int z = b >> 6;
  const int y0 = (b & 63) * 4;

  if (t < 256){ sk[t] = -1; sa[t] = 0; sp[t] = 0; }
  if (t < 144){
    int p = t / 48, q = (t / 8) % 6, s = t & 7;
    int zz = refl(z + p - 1, DD), yy = refl(y0 + q - 1, HH);
    sfg[t] = fgbits[(zz << 11) | (yy << 3) | s];
  }
  __syncthreads();

  if (t < 32){
    int ry = t >> 3, s = t & 7;
    auto W  = [&](int p, int q){ return sfg[p * 48 + q * 8 + s]; };
    auto WL = [&](int p, int q){
      unsigned w = W(p, q);
      unsigned c = (s > 0) ? ((sfg[p * 48 + q * 8 + s - 1] >> 31) & 1u) : ((w >> 1) & 1u);
      return (w << 1) | c;
    };
    auto WR = [&](int p, int q){
      unsigned w = W(p, q);
      unsigned c = (s < 7) ? ((sfg[p * 48 + q * 8 + s + 1] & 1u) << 31) : ((w & 0x40000000u) << 1);
      return (w >> 1) | c;
    };
    int qm = ry, qc = ry + 1, qp = ry + 2;
    unsigned own = W(1, qc);
    unsigned e = W(0, qm) & W(0, qp) & W(2, qm) & W(2, qp);     // (±1,±1,0)
    e &= W(0, qc) & WL(0, qc) & WR(0, qc);                      // (-1,0,*)
    e &= W(2, qc) & WL(2, qc) & WR(2, qc);                      // (+1,0,*)
    e &= W(1, qm) & WL(1, qm) & WR(1, qm);                      // (0,-1,*)
    e &= W(1, qp) & WL(1, qp) & WR(1, qp);                      // (0,+1,*)
    e &= WL(1, qc) & WR(1, qc);                                 // (0,0,±1)
    sbnd[t] = own & ~e;
  }
  __syncthreads();

  const int i = b * 1024 + t;
  int lab = parent[i];                     // tile-root label; -1 = bg
  int bnd = 0;
  if (lab >= 0){
    bnd = (sbnd[t >> 5] >> (t & 31)) & 1;
    // parallel READ-ONLY root resolution (chains short; latency hidden by TLP)
    int p = parent[lab];
    while (p != lab){ lab = p; p = parent[lab]; }
  }

  // wave reduce-by-key over FINAL roots (typically 1-2 distinct per wave)
  const int lane = t & 63;
  unsigned long long fgm = __ballot(lab >= 0);
  unsigned long long bm  = __ballot(bnd != 0);
  unsigned long long act = fgm;
  while (act){
    int leader = (int)__ffsll(act) - 1;
    int llab = __shfl(lab, leader);
    unsigned long long match = __ballot(lab == llab) & fgm;
    if (lane == leader){
      int a = (int)__popcll(match);
      int p = (int)__popcll(match & bm);
      unsigned h = ((unsigned)llab * 2654435761u) >> 24;
      bool done = false;
      for (int probe = 0; probe < 256; probe++){
        int old = atomicCAS(&sk[h], -1, llab);
        if (old == -1 || old == llab){
          atomicAdd(&sa[h], a);
          if (p) atomicAdd(&sp[h], p);
          done = true; break;
        }
        h = (h + 1) & 255;
      }
      if (!done) ghash_add(hkey, harea, hper, llab, a, p);
    }
    act &= ~match;
  }
  __syncthreads();
  // flush to one of NCOPY replicated hashes (spread same-address atomics)
  const int c = (b & (NCOPY - 1)) * GHS;
  if (t < 256 && sk[t] >= 0) ghash_add(hkey + c, harea + c, hper + c, sk[t], sa[t], sp[t]);
}

// ---------------- phase D: parallel merge of copies 1..15 into copy 0 ----------------
__global__ __launch_bounds__(256) void k_merge(int* __restrict__ hkey,
                                               int* __restrict__ harea,
                                               int* __restrict__ hper){
  const int j = GHS + blockIdx.x * 256 + threadIdx.x;   // grid covers (NCOPY-1)*GHS
  int key = hkey[j];
  if (key >= 0) ghash_add(hkey, harea, hper, key, harea[j], hper[j]);
}

// ---------------- phase E: scan copy 0 + finalize ----------------
__global__ __launch_bounds__(256) void k_fin(const int* __restrict__ hkey,
                                             const int* __restrict__ harea,
                                             const int* __restrict__ hper,
                                             float* __restrict__ out){
  __shared__ float ssum[256];
  const int t = threadIdx.x;
  float s = 0.0f;
  for (int j = t; j < GHS; j += 256){
    if (hkey[j] >= 0){
      float a = (float)harea[j];
      float p = (float)hper[j];
      s += 12.566370614359172f * a / (p * p + 1e-5f);
    }
  }
  ssum[t] = s;
  __syncthreads();
  for (int w = 128; w > 0; w >>= 1){
    if (t < w) ssum[t] += ssum[t + w];
    __syncthreads();
  }
  if (t == 0){
    float comp = ssum[0] / 64.0f;
    out[0] = 1.0f / (comp + 1e-5f);
  }
}

// ---------------- launcher ----------------
extern "C" void kernel_launch(void* const* d_in, const int* in_sizes, int n_in,
                              void* d_out, int out_size, void* d_ws, size_t ws_size,
                              hipStream_t stream){
  const float* y = (const float*)d_in[0];
  char* w = (char*)d_ws;
  int* parent            = (int*)w;                    w += (size_t)NN * 4;          // 16 MiB
  unsigned long long* ph = (unsigned long long*)w;     w += (size_t)PHS * 8;         // 1 MiB
  int* hkey              = (int*)w;                    w += (size_t)NCOPY * GHS * 4; // 256 KiB
  int* harea             = (int*)w;                    w += (size_t)NCOPY * GHS * 4;
  int* hper              = (int*)w;                    w += (size_t)NCOPY * GHS * 4;
  unsigned* fgbits       = (unsigned*)w;               w += (size_t)NSEG * 4;        // 512 KiB
  float* out = (float*)d_out;

  hipLaunchKernelGGL(k_local, dim3(512),       dim3(1024), 0, stream, y, parent, fgbits, hkey, harea, hper, ph);
  hipLaunchKernelGGL(k_pairs, dim3(CFACE/256), dim3(256),  0, stream, parent, fgbits, ph);
  hipLaunchKernelGGL(k_stats, dim3(NN/1024),   dim3(1024), 0, stream, parent, fgbits, hkey, harea, hper);
  hipLaunchKernelGGL(k_merge, dim3((NCOPY-1)*GHS/256), dim3(256), 0, stream, hkey, harea, hper);
  hipLaunchKernelGGL(k_fin,   dim3(1),         dim3(256),  0, stream, hkey, harea, hper, out);
}

// Round 13
// 162.393 us; speedup vs baseline: 1.0471x; 1.0390x over previous
//
#include <hip/hip_runtime.h>

#define DD 64
#define HH 256
#define WW 256
#define NN (DD*HH*WW)   // 4194304
#define GHS 4096        // stats-hash slots per copy (power of 2)
#define NCOPY 16        // replicated stats hashes (contention spread)
#define PHS 131072      // global pair-hash slots (power of 2, 64-bit keys)
#define NSEG (NN/32)    // 131072 bitmask words

// tile for local CCL phase
#define TZ 8
#define TY 32
#define TX 32
#define TVOX (TZ*TY*TX) // 8192 -> 32 KB LDS

// face-voxel enumeration for cross-tile pass
#define CA 458752            // 7 * 65536   (z-faces)
#define CB 114688            // 7 * 16384   (each of y0/y31/x0/x31 faces)
#define CFACE (CA + 4*CB)    // 917504 = 3584 * 256

// per-face backward offset subsets:
// T0 rows 0-8: all dz=-1 ; T1 rows 9-14: dy=-1 ; T2 rows 15-17: dy=+1(dz=-1)
// T3 rows 18-22: dx=-1   ; T4 rows 23-26: dx=+1
__device__ const signed char Foff[27][3] = {
  {-1,-1,-1},{-1,-1,0},{-1,-1,1},{-1,0,-1},{-1,0,0},{-1,0,1},{-1,1,-1},{-1,1,0},{-1,1,1},
  {-1,-1,-1},{-1,-1,0},{-1,-1,1},{0,-1,-1},{0,-1,0},{0,-1,1},
  {-1,1,-1},{-1,1,0},{-1,1,1},
  {-1,-1,-1},{-1,0,-1},{-1,1,-1},{0,-1,-1},{0,0,-1},
  {-1,-1,1},{-1,0,1},{-1,1,1},{0,-1,1}};
__device__ const int Fst[5] = {0, 9, 15, 18, 23};
__device__ const int Fct[5] = {9, 6, 3, 5, 4};

// ---------------- union-find (works on LDS or global) ----------------
// Safety: every write stores an ancestor and preserves P[x] <= x; 4B accesses
// are HW-atomic, so concurrent halving stores cannot lose connectivity.
__device__ __forceinline__ int ufind(int* P, int x){
  int p = P[x];
  while (p != x){
    int gp = P[p];
    if (gp != p) P[x] = gp;   // path halving
    x = gp;
    p = P[x];
  }
  return x;
}

__device__ __forceinline__ int ufind_ro(const int* P, int x){
  int p = P[x];
  while (p != x){ x = p; p = P[x]; }
  return x;
}

__device__ __forceinline__ void uunion(int* P, int a, int b){
  while (true){
    a = ufind(P, a);
    b = ufind(P, b);
    if (a == b) return;
    if (a < b){ int t = a; a = b; b = t; }   // link big -> small
    int old = atomicMin(&P[a], b);
    if (old == a) return;
    a = old;
  }
}

// run start of bit x in mask m (bit x must be set)
__device__ __forceinline__ int run_start(unsigned m, int x){
  unsigned zb = (~m) & ((x == 0) ? 0u : ((1u << x) - 1u));
  return (zb == 0) ? 0 : (32 - __builtin_clz(zb));
}

__device__ __forceinline__ int refl(int v, int L){ return v < 0 ? 1 : (v >= L ? L - 2 : v); }

// ---------------- phase A: run-granular tile-local CCL in LDS ----------------
__global__ __launch_bounds__(1024) void k_local(const float* __restrict__ in,
                                                int* __restrict__ parent,
                                                unsigned* __restrict__ fgbits,
                                                int* __restrict__ hkey,
                                                int* __restrict__ harea,
                                                int* __restrict__ hper,
                                                unsigned long long* __restrict__ ph){
  __shared__ int sl[TVOX];                // union-find nodes: run-start entries only
  __shared__ unsigned srow[256];          // fg mask per (lz,ly) row
  const int t = threadIdx.x;
  const int b = blockIdx.x;               // 512 tiles: 8 x 8 x 8
  const int z0 = (b >> 6) * TZ;
  const int y0 = ((b >> 3) & 7) * TY;
  const int x0 = (b & 7) * TX;

  // init 16 stats-hash copies (16*4096 = 65536 = 64 blocks x 1024)
  if (b < (NCOPY * GHS) / 1024){ int j = b * 1024 + t; hkey[j] = -1; harea[j] = 0; hper[j] = 0; }
  { int j = b * 1024 + t; if (j < PHS) ph[j] = ~0ULL; }   // pair hash sentinel

  // blocked mapping: thread t owns one byte (8 voxels) of row (t>>2)
  const int row = t >> 2;                 // (lz<<5)|ly
  const int xb  = (t & 3) * 8;
  const int lz  = row >> 5, ly = row & 31;
  const int gi0 = ((z0 + lz) << 16) | ((y0 + ly) << 8) | (x0 + xb);

  // A1: vectorized load -> fg byte -> row mask via 2 shuffle rounds
  float4 f0 = *(const float4*)(in + gi0);
  float4 f1 = *(const float4*)(in + gi0 + 4);
  int by = (f0.x > 0.5f)        | ((f0.y > 0.5f) << 1) |
           ((f0.z > 0.5f) << 2) | ((f0.w > 0.5f) << 3) |
           ((f1.x > 0.5f) << 4) | ((f1.y > 0.5f) << 5) |
           ((f1.z > 0.5f) << 6) | ((f1.w > 0.5f) << 7);
  int v1 = by | (__shfl_xor(by, 1) << 8);
  int v2 = v1 | (__shfl_xor(v1, 2) << 16);
  if ((t & 3) == 0){
    srow[row] = (unsigned)v2;
    fgbits[((z0 + lz) << 11) | ((y0 + ly) << 3) | (x0 >> 5)] = (unsigned)v2;
  }
  __syncthreads();

  const unsigned m = srow[row];
  const unsigned starts = m & ~(m << 1);           // all run starts of this row
  const unsigned sm = starts & (0xFFu << xb);      // starts within this thread's byte

  // A2: init ONLY run-start entries (the union-find never touches others)
  {
    unsigned w = sm;
    while (w){
      int s = __builtin_ctz(w); w &= w - 1;
      sl[(row << 5) | s] = (row << 5) | s;
    }
  }
  __syncthreads();

  // A3: run-granular unions; thread owning the run START handles the whole run
  const int rel[4][2] = {{-1,-1},{-1,0},{-1,1},{0,-1}};   // (dz,dy)
  {
    unsigned w0 = sm;
    while (w0){
      int x = __builtin_ctz(w0); w0 &= w0 - 1;
      unsigned zs = (~m) >> x;
      int len = zs ? __builtin_ctz(zs) : (32 - x);
      int end = x + len - 1;
      unsigned long long wmask = ((1ull << (end + 2)) - 1) &
                                 ~((x == 0) ? 0ull : ((1ull << (x - 1)) - 1));
      int self = (row << 5) | x;
      #pragma unroll
      for (int r = 0; r < 4; r++){
        int zz = lz + rel[r][0], yy = ly + rel[r][1];
        if (zz < 0 || yy < 0 || yy >= TY) continue;
        int nrow = (zz << 5) | yy;
        unsigned mN = srow[nrow];
        unsigned wm = mN & (unsigned)wmask;
        while (wm){
          int bb = __builtin_ctz(wm);
          int ns = run_start(mN, bb);
          uunion(sl, self, (nrow << 5) | ns);
          unsigned t2 = (~mN) >> bb;
          int l2 = t2 ? __builtin_ctz(t2) : (32 - bb);
          unsigned long long clr = (bb + l2 >= 32) ? 0xffffffffull : ((1ull << (bb + l2)) - 1);
          wm &= ~(unsigned)clr;
        }
      }
    }
  }
  __syncthreads();

  // A3.5: flatten run starts (read-only find; one final write per run start)
  {
    unsigned w = sm;
    while (w){
      int s = __builtin_ctz(w); w &= w - 1;
      int v = (row << 5) | s;
      sl[v] = ufind_ro(sl, v);
    }
  }
  __syncthreads();

  // A4: per-run label read + translate (once per run), fill 8 voxels, int4 store
  int lab[8];
  int cur = -1;
  #pragma unroll
  for (int k = 0; k < 8; k++){
    int x = xb + k;
    if (!((m >> x) & 1)){ lab[k] = -1; cur = -1; continue; }
    if (cur < 0){
      int rs = (k == 0) ? run_start(m, x) : x;     // k>0 & prev clear -> x is a start
      int r = sl[(row << 5) | rs];
      cur = ((z0 + (r >> 10)) << 16) | ((y0 + ((r >> 5) & 31)) << 8) | (x0 + (r & 31));
    }
    lab[k] = cur;
  }
  *(int4*)(parent + gi0)     = make_int4(lab[0], lab[1], lab[2], lab[3]);
  *(int4*)(parent + gi0 + 4) = make_int4(lab[4], lab[5], lab[6], lab[7]);
}

// ---------------- phase B: face pass — dedup pairs + inline union ----------------
__device__ __forceinline__ void phash_union(unsigned long long* H, unsigned long long key,
                                            int* parent){
  unsigned h = (unsigned)((key * 0x9E3779B97F4A7C15ull) >> 47);   // [0, 2^17)
  while (true){
    unsigned long long old = atomicCAS(&H[h], ~0ULL, key);
    if (old == ~0ULL){ uunion(parent, (int)(key >> 32), (int)(key & 0xffffffffu)); return; }
    if (old == key) return;
    h = (h + 1) & (PHS - 1);
  }
}

__global__ __launch_bounds__(256) void k_pairs(int* __restrict__ parent,
                                               const unsigned* __restrict__ fgbits,
                                               unsigned long long* __restrict__ ph){
  __shared__ unsigned long long pk[256];    // per-block pair-dedup hash
  const int t = threadIdx.x;
  const int lane = t & 63;
  pk[t] = ~0ULL;
  __syncthreads();

  const int id = blockIdx.x * 256 + t;
  int z, y, x, ot;
  if (id < CA){ ot = 0; z = ((id >> 16) + 1) << 3; y = (id >> 8) & 255; x = id & 255; }
  else {
    int q = id - CA;
    int f = q >> 14;            // 0..27
    int r = q & 16383;
    int g = f / 7, mm = f % 7;
    if      (g == 0){ ot = 1; y = (mm + 1) << 5;  z = r >> 8; x = r & 255; }
    else if (g == 1){ ot = 2; y = (mm << 5) + 31; z = r >> 8; x = r & 255; }
    else if (g == 2){ ot = 3; x = (mm + 1) << 5;  z = r >> 8; y = r & 255; }
    else            { ot = 4; x = (mm << 5) + 31; z = r >> 8; y = r & 255; }
  }
  // ot (and thus Fst/Fct) is wave-uniform: face chunks are 16384-aligned.
  const int i = (z << 16) | (y << 8) | x;
  const bool self_fg = (fgbits[(z << 11) | (y << 3) | (x >> 5)] >> (x & 31)) & 1;
  int a = self_fg ? parent[i] : -1;
  unsigned long long lastkey = ~0ULL;       // within-thread dedup (across offsets)
  const int st = Fst[ot], en = st + Fct[ot];
  for (int k = st; k < en; k++){
    // fully predicated body: every lane reaches the shfl
    int zz = z + Foff[k][0], yy = y + Foff[k][1], xx = x + Foff[k][2];
    bool v = self_fg && zz >= 0 && yy >= 0 && yy < HH && xx >= 0 && xx < WW;
    if (v) v = (fgbits[(zz << 11) | (yy << 3) | (xx >> 5)] >> (xx & 31)) & 1;
    int bl = -1;
    if (v) bl = parent[(zz << 16) | (yy << 8) | xx];
    int hi = a > bl ? a : bl, lo = a > bl ? bl : a;
    unsigned long long key = v ? (((unsigned long long)(unsigned)hi << 32) | (unsigned)lo)
                               : ~0ULL;
    // cross-lane dedup: adjacent lanes walk adjacent face voxels -> same pair
    unsigned long long prev = __shfl_up((long long)key, 1);
    bool ins = v && (key != lastkey) && !(lane > 0 && prev == key);
    if (v) lastkey = key;
    if (ins){
      unsigned h = (unsigned)((key * 0x9E3779B97F4A7C15ull) >> 56);  // [0,256)
      bool done = false;
      for (int probe = 0; probe < 256; probe++){
        unsigned long long old = atomicCAS(&pk[h], ~0ULL, key);
        if (old == ~0ULL || old == key){ done = true; break; }
        h = (h + 1) & 255;
      }
      if (!done) phash_union(ph, key, parent);   // LDS hash full -> global
    }
  }
  __syncthreads();
  if (pk[t] != ~0ULL) phash_union(ph, pk[t], parent);
}

// ---------------- phase C: fused block-local boundary + stats ----------------
__device__ __forceinline__ void ghash_add(int* hkey, int* harea, int* hper,
                                          int key, int a, int p){
  unsigned h = ((unsigned)key * 2654435761u) >> 20;   // [0,4096)
  while (true){
    int old = atomicCAS(&hkey[h], -1, key);
    if (old == -1 || old == key){
      atomicAdd(&harea[h], a);
      if (p) atomicAdd(&hper[h], p);
      return;
    }
    h = (h + 1) & (GHS - 1);
  }
}

__global__ __launch_bounds__(1024) void k_stats(const int* __restrict__ parent,
                                                const unsigned* __restrict__ fgbits,
                                                int* __restrict__ hkey,
                                                int* __restrict__ harea,
                                                int* __restrict__ hper){
  __shared__ unsigned sfg[144];            // 3 z-planes x 6 y-rows x 8 s-words
  __shared__ unsigned sbnd[32];
  __shared__ int sk[256], sa[256], sp[256];
  const int t = threadIdx.x;
  const int b = blockIdx.x;                // 4096 blocks; block = 4 y-rows at one z
  const int z = b >> 6;
  const int y0 = (b & 63) * 4;

  if (t < 256){ sk[t] = -1; sa[t] = 0; sp[t] = 0; }
  if (t < 144){
    int p = t / 48, q = (t / 8) % 6, s = t & 7;
    int zz = refl(z + p - 1, DD), yy = refl(y0 + q - 1, HH);
    sfg[t] = fgbits[(zz << 11) | (yy << 3) | s];
  }
  __syncthreads();

  if (t < 32){
    int ry = t >> 3, s = t & 7;
    auto W  = [&](int p, int q){ return sfg[p * 48 + q * 8 + s]; };
    auto WL = [&](int p, int q){
      unsigned w = W(p, q);
      unsigned c = (s > 0) ? ((sfg[p * 48 + q * 8 + s - 1] >> 31) & 1u) : ((w >> 1) & 1u);
      return (w << 1) | c;
    };
    auto WR = [&](int p, int q){
      unsigned w = W(p, q);
      unsigned c = (s < 7) ? ((sfg[p * 48 + q * 8 + s + 1] & 1u) << 31) : ((w & 0x40000000u) << 1);
      return (w >> 1) | c;
    };
    int qm = ry, qc = ry + 1, qp = ry + 2;
    unsigned own = W(1, qc);
    unsigned e = W(0, qm) & W(0, qp) & W(2, qm) & W(2, qp);     // (±1,±1,0)
    e &= W(0, qc) & WL(0, qc) & WR(0, qc);                      // (-1,0,*)
    e &= W(2, qc) & WL(2, qc) & WR(2, qc);                      // (+1,0,*)
    e &= W(1, qm) & WL(1, qm) & WR(1, qm);                      // (0,-1,*)
    e &= W(1, qp) & WL(1, qp) & WR(1, qp);                      // (0,+1,*)
    e &= WL(1, qc) & WR(1, qc);                                 // (0,0,±1)
    sbnd[t] = own & ~e;
  }
  __syncthreads();

  const int i = b * 1024 + t;
  int lab = parent[i];                     // tile-root label; -1 = bg
  int bnd = 0;
  if (lab >= 0){
    bnd = (sbnd[t >> 5] >> (t & 31)) & 1;
    // parallel READ-ONLY root resolution (chains short; latency hidden by TLP)
    int p = parent[lab];
    while (p != lab){ lab = p; p = parent[lab]; }
  }

  // wave reduce-by-key over FINAL roots (typically 1-2 distinct per wave)
  const int lane = t & 63;
  unsigned long long fgm = __ballot(lab >= 0);
  unsigned long long bm  = __ballot(bnd != 0);
  unsigned long long act = fgm;
  while (act){
    int leader = (int)__ffsll(act) - 1;
    int llab = __shfl(lab, leader);
    unsigned long long match = __ballot(lab == llab) & fgm;
    if (lane == leader){
      int a = (int)__popcll(match);
      int p = (int)__popcll(match & bm);
      unsigned h = ((unsigned)llab * 2654435761u) >> 24;
      bool done = false;
      for (int probe = 0; probe < 256; probe++){
        int old = atomicCAS(&sk[h], -1, llab);
        if (old == -1 || old == llab){
          atomicAdd(&sa[h], a);
          if (p) atomicAdd(&sp[h], p);
          done = true; break;
        }
        h = (h + 1) & 255;
      }
      if (!done) ghash_add(hkey, harea, hper, llab, a, p);
    }
    act &= ~match;
  }
  __syncthreads();
  // flush to one of NCOPY replicated hashes (spread same-address atomics)
  const int c = (b & (NCOPY - 1)) * GHS;
  if (t < 256 && sk[t] >= 0) ghash_add(hkey + c, harea + c, hper + c, sk[t], sa[t], sp[t]);
}

// ---------------- phase D: parallel merge of copies 1..15 into copy 0 ----------------
__global__ __launch_bounds__(256) void k_merge(int* __restrict__ hkey,
                                               int* __restrict__ harea,
                                               int* __restrict__ hper){
  const int j = GHS + blockIdx.x * 256 + threadIdx.x;   // grid covers (NCOPY-1)*GHS
  int key = hkey[j];
  if (key >= 0) ghash_add(hkey, harea, hper, key, harea[j], hper[j]);
}

// ---------------- phase E: scan copy 0 + finalize ----------------
__global__ __launch_bounds__(256) void k_fin(const int* __restrict__ hkey,
                                             const int* __restrict__ harea,
                                             const int* __restrict__ hper,
                                             float* __restrict__ out){
  __shared__ float ssum[256];
  const int t = threadIdx.x;
  float s = 0.0f;
  for (int j = t; j < GHS; j += 256){
    if (hkey[j] >= 0){
      float a = (float)harea[j];
      float p = (float)hper[j];
      s += 12.566370614359172f * a / (p * p + 1e-5f);
    }
  }
  ssum[t] = s;
  __syncthreads();
  for (int w = 128; w > 0; w >>= 1){
    if (t < w) ssum[t] += ssum[t + w];
    __syncthreads();
  }
  if (t == 0){
    float comp = ssum[0] / 64.0f;
    out[0] = 1.0f / (comp + 1e-5f);
  }
}

// ---------------- launcher ----------------
extern "C" void kernel_launch(void* const* d_in, const int* in_sizes, int n_in,
                              void* d_out, int out_size, void* d_ws, size_t ws_size,
                              hipStream_t stream){
  const float* y = (const float*)d_in[0];
  char* w = (char*)d_ws;
  int* parent            = (int*)w;                    w += (size_t)NN * 4;          // 16 MiB
  unsigned long long* ph = (unsigned long long*)w;     w += (size_t)PHS * 8;         // 1 MiB
  int* hkey              = (int*)w;                    w += (size_t)NCOPY * GHS * 4; // 256 KiB
  int* harea             = (int*)w;                    w += (size_t)NCOPY * GHS * 4;
  int* hper              = (int*)w;                    w += (size_t)NCOPY * GHS * 4;
  unsigned* fgbits       = (unsigned*)w;               w += (size_t)NSEG * 4;        // 512 KiB
  float* out = (float*)d_out;

  hipLaunchKernelGGL(k_local, dim3(512),       dim3(1024), 0, stream, y, parent, fgbits, hkey, harea, hper, ph);
  hipLaunchKernelGGL(k_pairs, dim3(CFACE/256), dim3(256),  0, stream, parent, fgbits, ph);
  hipLaunchKernelGGL(k_stats, dim3(NN/1024),   dim3(1024), 0, stream, parent, fgbits, hkey, harea, hper);
  hipLaunchKernelGGL(k_merge, dim3((NCOPY-1)*GHS/256), dim3(256), 0, stream, hkey, harea, hper);
  hipLaunchKernelGGL(k_fin,   dim3(1),         dim3(256),  0, stream, hkey, harea, hper, out);
}

// Round 14
// 151.542 us; speedup vs baseline: 1.1220x; 1.0716x over previous
//
#include <hip/hip_runtime.h>

#define DD 64
#define HH 256
#define WW 256
#define NN (DD*HH*WW)   // 4194304
#define GHS 4096        // stats-hash slots per copy (power of 2)
#define NCOPY 16        // replicated stats hashes (contention spread)
#define PHS 131072      // global pair-hash slots (power of 2, 64-bit keys)
#define NSEG (NN/32)    // 131072 bitmask words

// tile for local CCL phase
#define TZ 8
#define TY 32
#define TX 32
#define TVOX (TZ*TY*TX) // 8192 -> 32 KB LDS

// face-voxel enumeration for cross-tile pass
#define CA 458752            // 7 * 65536   (z-faces)
#define CB 114688            // 7 * 16384   (each of y0/y31/x0/x31 faces)
#define CFACE (CA + 4*CB)    // 917504 = 3584 * 256

// ---------------- union-find (works on LDS or global) ----------------
// Safety: every write stores an ancestor and preserves P[x] <= x; 4B accesses
// are HW-atomic, so concurrent halving stores cannot lose connectivity.
__device__ __forceinline__ int ufind(int* P, int x){
  int p = P[x];
  while (p != x){
    int gp = P[p];
    if (gp != p) P[x] = gp;   // path halving
    x = gp;
    p = P[x];
  }
  return x;
}

__device__ __forceinline__ int ufind_ro(const int* P, int x){
  int p = P[x];
  while (p != x){ x = p; p = P[x]; }
  return x;
}

__device__ __forceinline__ void uunion(int* P, int a, int b){
  while (true){
    a = ufind(P, a);
    b = ufind(P, b);
    if (a == b) return;
    if (a < b){ int t = a; a = b; b = t; }   // link big -> small
    int old = atomicMin(&P[a], b);
    if (old == a) return;
    a = old;
  }
}

// run start of bit x in mask m (bit x must be set)
__device__ __forceinline__ int run_start(unsigned m, int x){
  unsigned zb = (~m) & ((x == 0) ? 0u : ((1u << x) - 1u));
  return (zb == 0) ? 0 : (32 - __builtin_clz(zb));
}

__device__ __forceinline__ int refl(int v, int L){ return v < 0 ? 1 : (v >= L ? L - 2 : v); }

// ---------------- phase A: run-granular tile-local CCL, worklist-balanced ----------------
__global__ __launch_bounds__(1024) void k_local(const float* __restrict__ in,
                                                int* __restrict__ parent,
                                                unsigned* __restrict__ fgbits,
                                                int* __restrict__ hkey,
                                                int* __restrict__ harea,
                                                int* __restrict__ hper,
                                                unsigned long long* __restrict__ ph){
  __shared__ int sl[TVOX];                // union-find nodes: run-start entries only
  __shared__ unsigned srow[256];          // fg mask per (lz,ly) row
  __shared__ int q[4096];                 // run-start worklist (max 16 runs/row * 256)
  __shared__ int qn;
  const int t = threadIdx.x;
  const int lane = t & 63;
  const int b = blockIdx.x;               // 512 tiles: 8 x 8 x 8
  const int z0 = (b >> 6) * TZ;
  const int y0 = ((b >> 3) & 7) * TY;
  const int x0 = (b & 7) * TX;

  // init 16 stats-hash copies (16*4096 = 65536 = 64 blocks x 1024)
  if (b < (NCOPY * GHS) / 1024){ int j = b * 1024 + t; hkey[j] = -1; harea[j] = 0; hper[j] = 0; }
  { int j = b * 1024 + t; if (j < PHS) ph[j] = ~0ULL; }   // pair hash sentinel
  if (t == 0) qn = 0;

  // blocked mapping: thread t owns one byte (8 voxels) of row (t>>2)
  const int row = t >> 2;                 // (lz<<5)|ly
  const int xb  = (t & 3) * 8;
  const int lz  = row >> 5, ly = row & 31;
  const int gi0 = ((z0 + lz) << 16) | ((y0 + ly) << 8) | (x0 + xb);

  // A1: vectorized load -> fg byte -> row mask via 2 shuffle rounds
  float4 f0 = *(const float4*)(in + gi0);
  float4 f1 = *(const float4*)(in + gi0 + 4);
  int by = (f0.x > 0.5f)        | ((f0.y > 0.5f) << 1) |
           ((f0.z > 0.5f) << 2) | ((f0.w > 0.5f) << 3) |
           ((f1.x > 0.5f) << 4) | ((f1.y > 0.5f) << 5) |
           ((f1.z > 0.5f) << 6) | ((f1.w > 0.5f) << 7);
  int v1 = by | (__shfl_xor(by, 1) << 8);
  int v2 = v1 | (__shfl_xor(v1, 2) << 16);
  if ((t & 3) == 0){
    srow[row] = (unsigned)v2;
    fgbits[((z0 + lz) << 11) | ((y0 + ly) << 3) | (x0 >> 5)] = (unsigned)v2;
  }
  __syncthreads();

  const unsigned m = srow[row];
  const unsigned starts = m & ~(m << 1);           // all run starts of this row
  const unsigned sm = starts & (0xFFu << xb);      // starts within this thread's byte

  // A2: init run-start entries + push to balanced worklist (wave prefix-scan)
  {
    int cnt = __popc(sm);
    int pre = cnt;
    #pragma unroll
    for (int d = 1; d < 64; d <<= 1){
      int v = __shfl_up(pre, d);
      if (lane >= d) pre += v;
    }
    int tot = __shfl(pre, 63);              // wave total (inclusive at lane 63)
    int bw = 0;
    if (lane == 63) bw = atomicAdd(&qn, tot);
    bw = __shfl(bw, 63);
    int pos = bw + pre - cnt;               // exclusive offset
    unsigned w = sm;
    while (w){
      int s = __builtin_ctz(w); w &= w - 1;
      int v = (row << 5) | s;
      sl[v] = v;
      q[pos++] = v;
    }
  }
  __syncthreads();
  const int NQ = qn;

  // A3: run-granular unions over the balanced worklist
  const int rel[4][2] = {{-1,-1},{-1,0},{-1,1},{0,-1}};   // (dz,dy)
  for (int it = t; it < NQ; it += 1024){
    int v = q[it];
    int vrow = v >> 5, x = v & 31;
    unsigned mr = srow[vrow];
    unsigned zs = (~mr) >> x;
    int len = zs ? __builtin_ctz(zs) : (32 - x);
    int end = x + len - 1;
    unsigned long long wmask = ((1ull << (end + 2)) - 1) &
                               ~((x == 0) ? 0ull : ((1ull << (x - 1)) - 1));
    int vlz = vrow >> 5, vly = vrow & 31;
    #pragma unroll
    for (int r = 0; r < 4; r++){
      int zz = vlz + rel[r][0], yy = vly + rel[r][1];
      if (zz < 0 || yy < 0 || yy >= TY) continue;
      int nrow = (zz << 5) | yy;
      unsigned mN = srow[nrow];
      unsigned wm = mN & (unsigned)wmask;
      while (wm){
        int bb = __builtin_ctz(wm);
        int ns = run_start(mN, bb);
        uunion(sl, v, (nrow << 5) | ns);
        unsigned t2 = (~mN) >> bb;
        int l2 = t2 ? __builtin_ctz(t2) : (32 - bb);
        unsigned long long clr = (bb + l2 >= 32) ? 0xffffffffull : ((1ull << (bb + l2)) - 1);
        wm &= ~(unsigned)clr;
      }
    }
  }
  __syncthreads();

  // A3.5: flatten run starts (read-only find; one final write per run start)
  for (int it = t; it < NQ; it += 1024){
    int v = q[it];
    sl[v] = ufind_ro(sl, v);
  }
  __syncthreads();

  // A4: per-run label read + translate (once per run), fill 8 voxels, int4 store
  int lab[8];
  int cur = -1;
  #pragma unroll
  for (int k = 0; k < 8; k++){
    int x = xb + k;
    if (!((m >> x) & 1)){ lab[k] = -1; cur = -1; continue; }
    if (cur < 0){
      int rs = (k == 0) ? run_start(m, x) : x;     // k>0 & prev clear -> x is a start
      int r = sl[(row << 5) | rs];
      cur = ((z0 + (r >> 10)) << 16) | ((y0 + ((r >> 5) & 31)) << 8) | (x0 + (r & 31));
    }
    lab[k] = cur;
  }
  *(int4*)(parent + gi0)     = make_int4(lab[0], lab[1], lab[2], lab[3]);
  *(int4*)(parent + gi0 + 4) = make_int4(lab[4], lab[5], lab[6], lab[7]);
}

// ---------------- phase B: face pass — row-run pair enumeration + inline union ----------------
__device__ __forceinline__ void phash_union(unsigned long long* H, unsigned long long key,
                                            int* parent){
  unsigned h = (unsigned)((key * 0x9E3779B97F4A7C15ull) >> 47);   // [0, 2^17)
  while (true){
    unsigned long long old = atomicCAS(&H[h], ~0ULL, key);
    if (old == ~0ULL){ uunion(parent, (int)(key >> 32), (int)(key & 0xffffffffu)); return; }
    if (old == key) return;
    h = (h + 1) & (PHS - 1);
  }
}

__global__ __launch_bounds__(256) void k_pairs(int* __restrict__ parent,
                                               const unsigned* __restrict__ fgbits,
                                               unsigned long long* __restrict__ ph){
  __shared__ unsigned long long pk[256];    // per-block pair-dedup hash
  const int t = threadIdx.x;
  pk[t] = ~0ULL;
  __syncthreads();

  const int id = blockIdx.x * 256 + t;
  int z, y, x, ot;
  if (id < CA){ ot = 0; z = ((id >> 16) + 1) << 3; y = (id >> 8) & 255; x = id & 255; }
  else {
    int q = id - CA;
    int f = q >> 14;            // 0..27
    int r = q & 16383;
    int g = f / 7, mm = f % 7;
    if      (g == 0){ ot = 1; y = (mm + 1) << 5;  z = r >> 8; x = r & 255; }
    else if (g == 1){ ot = 2; y = (mm << 5) + 31; z = r >> 8; x = r & 255; }
    else if (g == 2){ ot = 3; x = (mm + 1) << 5;  z = r >> 8; y = r & 255; }
    else            { ot = 4; x = (mm << 5) + 31; z = r >> 8; y = r & 255; }
  }
  const int s = x >> 5, xl = x & 31;
  const unsigned wself = fgbits[(z << 11) | (y << 3) | s];
  if ((wself >> xl) & 1){
    const int a = parent[(z << 16) | (y << 8) | x];
    unsigned long long lastkey = ~0ULL;

    auto do_pair = [&](int zz, int yy, int xc){
      int bl = parent[(zz << 16) | (yy << 8) | xc];
      int hi = a > bl ? a : bl, lo = a > bl ? bl : a;
      unsigned long long key = ((unsigned long long)(unsigned)hi << 32) | (unsigned)lo;
      if (key == lastkey) return;
      lastkey = key;
      unsigned h = (unsigned)((key * 0x9E3779B97F4A7C15ull) >> 56);  // [0,256)
      for (int probe = 0; probe < 256; probe++){
        unsigned long long old = atomicCAS(&pk[h], ~0ULL, key);
        if (old == ~0ULL || old == key) return;
        h = (h + 1) & 255;
      }
      phash_union(ph, key, parent);          // LDS hash full -> global
    };

    // row relation: dx in {-1,0,1} vs one fg word; center set => x+-1 same run
    auto do_row = [&](int zz, int yy){
      if (zz < 0 || yy < 0 || yy >= HH) return;
      unsigned mN = fgbits[(zz << 11) | (yy << 3) | s];
      if ((mN >> xl) & 1){ do_pair(zz, yy, x); return; }
      bool l = (xl > 0) ? ((mN >> (xl - 1)) & 1)
                        : (x > 0 && ((fgbits[(zz << 11) | (yy << 3) | (s - 1)] >> 31) & 1));
      bool r = (xl < 31) ? ((mN >> (xl + 1)) & 1)
                         : (x < WW - 1 && (fgbits[(zz << 11) | (yy << 3) | (s + 1)] & 1));
      if (l) do_pair(zz, yy, x - 1);
      if (r) do_pair(zz, yy, x + 1);
    };

    auto do_bit = [&](int zz, int yy, int xc){   // single-voxel check (x-face types)
      if (zz < 0 || yy < 0 || yy >= HH) return;
      unsigned mN = fgbits[(zz << 11) | (yy << 3) | (xc >> 5)];
      if ((mN >> (xc & 31)) & 1) do_pair(zz, yy, xc);
    };

    switch (ot){
      case 0: do_row(z-1, y-1); do_row(z-1, y); do_row(z-1, y+1); break;
      case 1: do_row(z-1, y-1); do_row(z, y-1); break;
      case 2: do_row(z-1, y+1); break;
      case 3: do_bit(z-1, y-1, x-1); do_bit(z-1, y, x-1); do_bit(z-1, y+1, x-1);
              do_bit(z,   y-1, x-1); do_bit(z,   y, x-1); break;
      case 4: do_bit(z-1, y-1, x+1); do_bit(z-1, y, x+1); do_bit(z-1, y+1, x+1);
              do_bit(z,   y-1, x+1); break;
    }
  }
  __syncthreads();
  if (pk[t] != ~0ULL) phash_union(ph, pk[t], parent);
}

// ---------------- phase C: fused block-local boundary + stats ----------------
__device__ __forceinline__ void ghash_add(int* hkey, int* harea, int* hper,
                                          int key, int a, int p){
  unsigned h = ((unsigned)key * 2654435761u) >> 20;   // [0,4096)
  while (true){
    int old = atomicCAS(&hkey[h], -1, key);
    if (old == -1 || old == key){
      atomicAdd(&harea[h], a);
      if (p) atomicAdd(&hper[h], p);
      return;
    }
    h = (h + 1) & (GHS - 1);
  }
}

__global__ __launch_bounds__(1024) void k_stats(const int* __restrict__ parent,
                                                const unsigned* __restrict__ fgbits,
                                                int* __restrict__ hkey,
                                                int* __restrict__ harea,
                                                int* __restrict__ hper){
  __shared__ unsigned sfg[144];            // 3 z-planes x 6 y-rows x 8 s-words
  __shared__ unsigned sbnd[32];
  __shared__ int sk[256], sa[256], sp[256];
  const int t = threadIdx.x;
  const int b = blockIdx.x;                // 4096 blocks; block = 4 y-rows at one z
  const int z = b >> 6;
  const int y0 = (b & 63) * 4;

  if (t < 256){ sk[t] = -1; sa[t] = 0; sp[t] = 0; }
  if (t < 144){
    int p = t / 48, q = (t / 8) % 6, s = t & 7;
    int zz = refl(z + p - 1, DD), yy = refl(y0 + q - 1, HH);
    sfg[t] = fgbits[(zz << 11) | (yy << 3) | s];
  }
  __syncthreads();

  if (t < 32){
    int ry = t >> 3, s = t & 7;
    auto W  = [&](int p, int q){ return sfg[p * 48 + q * 8 + s]; };
    auto WL = [&](int p, int q){
      unsigned w = W(p, q);
      unsigned c = (s > 0) ? ((sfg[p * 48 + q * 8 + s - 1] >> 31) & 1u) : ((w >> 1) & 1u);
      return (w << 1) | c;
    };
    auto WR = [&](int p, int q){
      unsigned w = W(p, q);
      unsigned c = (s < 7) ? ((sfg[p * 48 + q * 8 + s + 1] & 1u) << 31) : ((w & 0x40000000u) << 1);
      return (w >> 1) | c;
    };
    int qm = ry, qc = ry + 1, qp = ry + 2;
    unsigned own = W(1, qc);
    unsigned e = W(0, qm) & W(0, qp) & W(2, qm) & W(2, qp);     // (±1,±1,0)
    e &= W(0, qc) & WL(0, qc) & WR(0, qc);                      // (-1,0,*)
    e &= W(2, qc) & WL(2, qc) & WR(2, qc);                      // (+1,0,*)
    e &= W(1, qm) & WL(1, qm) & WR(1, qm);                      // (0,-1,*)
    e &= W(1, qp) & WL(1, qp) & WR(1, qp);                      // (0,+1,*)
    e &= WL(1, qc) & WR(1, qc);                                 // (0,0,±1)
    sbnd[t] = own & ~e;
  }
  __syncthreads();

  const int i = b * 1024 + t;
  int lab = parent[i];                     // tile-root label; -1 = bg
  int bnd = 0;
  if (lab >= 0){
    bnd = (sbnd[t >> 5] >> (t & 31)) & 1;
    // parallel READ-ONLY root resolution (chains short; latency hidden by TLP)
    int p = parent[lab];
    while (p != lab){ lab = p; p = parent[lab]; }
  }

  // wave reduce-by-key over FINAL roots (typically 1-2 distinct per wave)
  const int lane = t & 63;
  unsigned long long fgm = __ballot(lab >= 0);
  unsigned long long bm  = __ballot(bnd != 0);
  unsigned long long act = fgm;
  while (act){
    int leader = (int)__ffsll(act) - 1;
    int llab = __shfl(lab, leader);
    unsigned long long match = __ballot(lab == llab) & fgm;
    if (lane == leader){
      int a = (int)__popcll(match);
      int p = (int)__popcll(match & bm);
      unsigned h = ((unsigned)llab * 2654435761u) >> 24;
      bool done = false;
      for (int probe = 0; probe < 256; probe++){
        int old = atomicCAS(&sk[h], -1, llab);
        if (old == -1 || old == llab){
          atomicAdd(&sa[h], a);
          if (p) atomicAdd(&sp[h], p);
          done = true; break;
        }
        h = (h + 1) & 255;
      }
      if (!done) ghash_add(hkey, harea, hper, llab, a, p);
    }
    act &= ~match;
  }
  __syncthreads();
  // flush to one of NCOPY replicated hashes (spread same-address atomics)
  const int c = (b & (NCOPY - 1)) * GHS;
  if (t < 256 && sk[t] >= 0) ghash_add(hkey + c, harea + c, hper + c, sk[t], sa[t], sp[t]);
}

// ---------------- phase D: parallel merge of copies 1..15 into copy 0 ----------------
__global__ __launch_bounds__(256) void k_merge(int* __restrict__ hkey,
                                               int* __restrict__ harea,
                                               int* __restrict__ hper){
  const int j = GHS + blockIdx.x * 256 + threadIdx.x;   // grid covers (NCOPY-1)*GHS
  int key = hkey[j];
  if (key >= 0) ghash_add(hkey, harea, hper, key, harea[j], hper[j]);
}

// ---------------- phase E: scan copy 0 + finalize ----------------
__global__ __launch_bounds__(256) void k_fin(const int* __restrict__ hkey,
                                             const int* __restrict__ harea,
                                             const int* __restrict__ hper,
                                             float* __restrict__ out){
  __shared__ float ssum[256];
  const int t = threadIdx.x;
  float s = 0.0f;
  for (int j = t; j < GHS; j += 256){
    if (hkey[j] >= 0){
      float a = (float)harea[j];
      float p = (float)hper[j];
      s += 12.566370614359172f * a / (p * p + 1e-5f);
    }
  }
  ssum[t] = s;
  __syncthreads();
  for (int w = 128; w > 0; w >>= 1){
    if (t < w) ssum[t] += ssum[t + w];
    __syncthreads();
  }
  if (t == 0){
    float comp = ssum[0] / 64.0f;
    out[0] = 1.0f / (comp + 1e-5f);
  }
}

// ---------------- launcher ----------------
extern "C" void kernel_launch(void* const* d_in, const int* in_sizes, int n_in,
                              void* d_out, int out_size, void* d_ws, size_t ws_size,
                              hipStream_t stream){
  const float* y = (const float*)d_in[0];
  char* w = (char*)d_ws;
  int* parent            = (int*)w;                    w += (size_t)NN * 4;          // 16 MiB
  unsigned long long* ph = (unsigned long long*)w;     w += (size_t)PHS * 8;         // 1 MiB
  int* hkey              = (int*)w;                    w += (size_t)NCOPY * GHS * 4; // 256 KiB
  int* harea             = (int*)w;                    w += (size_t)NCOPY * GHS * 4;
  int* hper              = (int*)w;                    w += (size_t)NCOPY * GHS * 4;
  unsigned* fgbits       = (unsigned*)w;               w += (size_t)NSEG * 4;        // 512 KiB
  float* out = (float*)d_out;

  hipLaunchKernelGGL(k_local, dim3(512),       dim3(1024), 0, stream, y, parent, fgbits, hkey, harea, hper, ph);
  hipLaunchKernelGGL(k_pairs, dim3(CFACE/256), dim3(256),  0, stream, parent, fgbits, ph);
  hipLaunchKernelGGL(k_stats, dim3(NN/1024),   dim3(1024), 0, stream, parent, fgbits, hkey, harea, hper);
  hipLaunchKernelGGL(k_merge, dim3((NCOPY-1)*GHS/256), dim3(256), 0, stream, hkey, harea, hper);
  hipLaunchKernelGGL(k_fin,   dim3(1),         dim3(256),  0, stream, hkey, harea, hper, out);
}